// Round 6
// baseline (301.993 us; speedup 1.0000x reference)
//
#include <hip/hip_runtime.h>
#include <math.h>

typedef unsigned short u16;
typedef __attribute__((ext_vector_type(8))) short bf16x8;
typedef __attribute__((ext_vector_type(4))) float f32x4;

#define D_MODEL 256
#define T_SZ 1024
constexpr size_t S_ELT = (size_t)8192 * 256;
constexpr size_t MB = 1024 * 1024;

// workspace byte offsets (56MB footprint)
constexpr size_t OFF_QK = 0;            // u16 [8192][512] Q|K (8MB), steps in_proj..attn
constexpr size_t OFF_ATTN = 8 * MB;     // u16 [8192][256] (4MB), attn..outproj
constexpr size_t OFF_F = 0;             // u16 [8192][1024] (16MB), ffn1..ffn2 (qk/attn dead)
constexpr size_t OFF_VT = 16 * MB;      // u16 [8][4][64][1024] (4MB), in_proj..attn
constexpr size_t OFF_X = 16 * MB;       // f32 [8192][256] (8MB), LN1.. end (vt dead)
constexpr size_t OFF_COMB = 24 * MB;    // u16 [8192][512] conv|ema (8MB), emaconv..t1
constexpr size_t OFF_PRBF = 24 * MB;    // u16 [8192][256] (4MB), wconv..in_proj (dead before comb)
constexpr size_t OFF_XBF = 32 * MB;     // u16 [8192][256] (4MB), LN1..ffn1
constexpr size_t OFF_FB = 36 * MB;      // f32 [8192][256] deltas (8MB), t2..ln3
constexpr size_t OFF_WB = 44 * MB;      // u16 weights
constexpr size_t OFF_W1X = OFF_WB + 2883584;        // u16 [512][256]
constexpr size_t OFF_W1S = OFF_W1X + 262144;        // u16 [1024][256]
constexpr size_t OFF_SCR = OFF_W1S + 524288;        // f32 65536 (shared: ema then cs)
constexpr size_t OFF_B1X = OFF_SCR + 262144;        // f32 512
constexpr size_t OFF_B1S = OFF_B1X + 2048;          // f32 1024
constexpr size_t OFF_H = 48 * MB;       // u16 [8192][512] (8MB), t1..t2
constexpr size_t OFF_STATES = 48 * MB;  // u16 [8192][256] (4MB), ln3..ffn1 (h dead)

// bf16 weight element offsets inside WB
constexpr int WB_INPROJ = 0;
constexpr int WB_OUTPROJ = 196608;
constexpr int WB_P2S = 262144;   // unused after folding (kept for layout)
constexpr int WB_S2P = 327680;   // unused after folding
constexpr int WB_T1 = 393216;
constexpr int WB_T2 = 786432;
constexpr int WB_F1 = 917504;
constexpr int WB_F2 = 1179648;
constexpr int WB_TOTAL = 1441792;
constexpr int PR_TOTAL = 2097152;

__device__ __forceinline__ u16 f2bf(float f) {
  unsigned int u = __float_as_uint(f);
  u += 0x7fff + ((u >> 16) & 1);
  return (u16)(u >> 16);
}
__device__ __forceinline__ float bf2f(u16 s) {
  return __uint_as_float(((unsigned int)s) << 16);
}

// async global -> LDS, 16B per lane; LDS dst is wave-uniform base + lane*16B.
__device__ __forceinline__ void glds16(const u16* g, u16* l) {
  __builtin_amdgcn_global_load_lds(
      (const __attribute__((address_space(1))) void*)g,
      (__attribute__((address_space(3))) void*)l, 16, 0, 0);
}

__device__ __forceinline__ float block_reduce_sum(float v, float* tmp) {
#pragma unroll
  for (int o = 32; o > 0; o >>= 1) v += __shfl_down(v, o);
  const int lane = threadIdx.x & 63, wid = threadIdx.x >> 6;
  if (lane == 0) tmp[wid] = v;
  __syncthreads();
  v = tmp[0] + tmp[1] + tmp[2] + tmp[3];
  __syncthreads();
  return v;
}

// ---------------------------------------------------------------------------
// weight + parallel_repr fp32 -> bf16 conversion (single kernel)
// ---------------------------------------------------------------------------
__global__ __launch_bounds__(256)
void wconv_kernel(const float* w0, const float* w1, const float* w2,
                  const float* w3, const float* w4, const float* w5,
                  const float* w6, const float* w7, const float* pr,
                  u16* __restrict__ wb, u16* __restrict__ prb) {
  const int idx4 = (blockIdx.x * 256 + threadIdx.x) * 4;
  if (idx4 < WB_TOTAL) {
    const int offs[9] = {WB_INPROJ, WB_OUTPROJ, WB_P2S,  WB_S2P, WB_T1,
                         WB_T2,     WB_F1,      WB_F2,   WB_TOTAL};
    const float* srcs[8] = {w0, w1, w2, w3, w4, w5, w6, w7};
    int seg = 0;
    while (idx4 >= offs[seg + 1]) ++seg;
    float4 v = *(const float4*)(srcs[seg] + (idx4 - offs[seg]));
    unsigned int lo = (unsigned int)f2bf(v.x) | ((unsigned int)f2bf(v.y) << 16);
    unsigned int hi = (unsigned int)f2bf(v.z) | ((unsigned int)f2bf(v.w) << 16);
    *(uint2*)(wb + idx4) = make_uint2(lo, hi);
  } else {
    const int i4 = idx4 - WB_TOTAL;
    if (i4 < PR_TOTAL) {
      float4 v = *(const float4*)(pr + i4);
      unsigned int lo = (unsigned int)f2bf(v.x) | ((unsigned int)f2bf(v.y) << 16);
      unsigned int hi = (unsigned int)f2bf(v.z) | ((unsigned int)f2bf(v.w) << 16);
      *(uint2*)(prb + i4) = make_uint2(lo, hi);
    }
  }
}

// ---------------------------------------------------------------------------
// Weight folding: W1x = t1[:, :256] + 0.3 * t1[:, :256] @ p2s      [512][256]
//                 W1s = 0.3 * ffn1 @ s2p                           [1024][256]
//                 bias1x = trans_b1 + 0.3 * t1[:, :256] @ p2s_b
//                 bias1s = ffn_b1  + 0.3 * ffn1 @ s2p_b
// ---------------------------------------------------------------------------
__global__ __launch_bounds__(256)
void wfold_kernel(const float* __restrict__ t1, const float* __restrict__ tb1,
                  const float* __restrict__ p2s, const float* __restrict__ p2sb,
                  const float* __restrict__ f1, const float* __restrict__ fb1,
                  const float* __restrict__ s2p, const float* __restrict__ s2pb,
                  u16* __restrict__ w1x, u16* __restrict__ w1s,
                  float* __restrict__ b1x, float* __restrict__ b1s) {
  __shared__ float tmp[4];
  const int n = blockIdx.x, i = threadIdx.x;
  if (n < 512) {
    const float* arow = t1 + (size_t)n * 768;
    float acc = 0.f;
#pragma unroll 8
    for (int k = 0; k < 256; ++k) acc = fmaf(arow[k], p2s[k * 256 + i], acc);
    w1x[n * 256 + i] = f2bf(arow[i] + 0.3f * acc);
    float s = block_reduce_sum(arow[i] * p2sb[i], tmp);
    if (i == 0) b1x[n] = tb1[n] + 0.3f * s;
  } else {
    const int m = n - 512;
    const float* arow = f1 + (size_t)m * 256;
    float acc = 0.f;
#pragma unroll 8
    for (int k = 0; k < 256; ++k) acc = fmaf(arow[k], s2p[k * 256 + i], acc);
    w1s[m * 256 + i] = f2bf(0.3f * acc);
    float s = block_reduce_sum(arow[i] * s2pb[i], tmp);
    if (i == 0) b1s[m] = fb1[m] + 0.3f * s;
  }
}

// ---------------------------------------------------------------------------
// bf16 MFMA GEMM, fragment-ordered async LDS staging, BK=64.
// A and W may be split at k=ksplit between two sources (folded-weight GEMMs).
// EPI_LN (BM=64,BN=256): full row per wave -> fused residual-add + LayerNorm.
// VSPLIT (in_proj): cols >=512 written transposed to vt.
// ---------------------------------------------------------------------------
enum { EPI_NONE = 0, EPI_GELU = 1, EPI_LN = 2 };

template <int EPI, int BM, int BN, bool OUTBF, bool VSPLIT>
__global__ __launch_bounds__(256, (BN == 256 ? 1 : 4))
void mgemm(const u16* __restrict__ A1, int lda1, const u16* __restrict__ A2,
           int lda2, int ksplit, const u16* __restrict__ W1, int ldw1,
           const u16* __restrict__ W2, int ldw2, int woff2, int K,
           const float* __restrict__ bias, void* __restrict__ Cv, int ldc,
           const float* __restrict__ addsrc, const float* __restrict__ lng,
           const float* __restrict__ lnb, u16* __restrict__ obf,
           u16* __restrict__ vt) {
  __shared__ u16 As[BM * 64];
  __shared__ u16 Bs[BN * 64];
  const int tid = threadIdx.x;
  const int w = tid >> 6, lane = tid & 63;
  const int ln = lane & 15, quad = lane >> 4;
  const int m0 = blockIdx.x * BM;
  const int n0 = blockIdx.y * BN;
  constexpr int MT = BM / 64;   // rows per wave = MT*16 (4 waves split rows)
  constexpr int NT = BN / 16;   // col fragments per wave (all waves all cols)
  const int wm = w * (MT * 16);
  constexpr int APW = BM / 64;  // A 16-row groups per wave per sub-step
  constexpr int BPW = BN / 64;

  f32x4 acc[MT][NT] = {};

  const int grow = lane >> 2;      // row within 16-row group
  const int gk8 = (lane & 3) * 8;  // k element offset

  for (int k0 = 0; k0 < K; k0 += 64) {
#pragma unroll
    for (int s = 0; s < 2; ++s) {
      const int kb = k0 + s * 32;
      const bool r1 = kb < ksplit;
      const u16* Ab = r1 ? A1 : A2;
      const int alda = r1 ? lda1 : lda2;
      const int ak = r1 ? kb : kb - ksplit;
#pragma unroll
      for (int p = 0; p < APW; ++p) {
        const int g = w * APW + p;
        glds16(Ab + (size_t)(m0 + g * 16 + grow) * alda + ak + gk8,
               As + s * BM * 32 + g * 512);
      }
      const u16* Wb = r1 ? W1 : W2;
      const int wlda = r1 ? ldw1 : ldw2;
      const int wk = r1 ? kb : kb - woff2;
#pragma unroll
      for (int p = 0; p < BPW; ++p) {
        const int g = w * BPW + p;
        glds16(Wb + (size_t)(n0 + g * 16 + grow) * wlda + wk + gk8,
               Bs + s * BN * 32 + g * 512);
      }
    }
    __syncthreads();  // drains vmcnt -> LDS valid
#pragma unroll
    for (int s = 0; s < 2; ++s) {
      const u16* abase = As + s * BM * 32 + (wm >> 4) * 512 + ln * 32 + quad * 8;
      const u16* bbase = Bs + s * BN * 32 + ln * 32 + quad * 8;
      bf16x8 af[MT], bv[NT];
#pragma unroll
      for (int i = 0; i < MT; ++i) af[i] = *(const bf16x8*)(abase + i * 512);
#pragma unroll
      for (int j = 0; j < NT; ++j) bv[j] = *(const bf16x8*)(bbase + j * 512);
#pragma unroll
      for (int i = 0; i < MT; ++i)
#pragma unroll
        for (int j = 0; j < NT; ++j)
          acc[i][j] = __builtin_amdgcn_mfma_f32_16x16x32_bf16(af[i], bv[j],
                                                              acc[i][j], 0, 0, 0);
    }
    __syncthreads();
  }

  if (EPI == EPI_LN) {
    // BM=64, BN=256, n0=0: wave holds 16 full rows. v = acc + bias + addsrc.
    float vals[NT][4];
    float s1[4] = {}, s2[4] = {};
#pragma unroll
    for (int j = 0; j < NT; ++j) {
      const int col = j * 16 + ln;
      const float bsv = bias[col];
      const int row0 = m0 + wm + quad * 4;
#pragma unroll
      for (int r = 0; r < 4; ++r) {
        float v = acc[0][j][r] + bsv + addsrc[(size_t)(row0 + r) * 256 + col];
        vals[j][r] = v;
        s1[r] += v;
        s2[r] += v * v;
      }
    }
#pragma unroll
    for (int r = 0; r < 4; ++r)
#pragma unroll
      for (int m = 1; m <= 8; m <<= 1) {
        s1[r] += __shfl_xor(s1[r], m, 64);
        s2[r] += __shfl_xor(s2[r], m, 64);
      }
#pragma unroll
    for (int r = 0; r < 4; ++r) {
      const int row = m0 + wm + quad * 4 + r;
      const float mean = s1[r] * (1.f / 256.f);
      const float var = s2[r] * (1.f / 256.f) - mean * mean;
      const float rstd = rsqrtf(var + 1e-5f);
#pragma unroll
      for (int j = 0; j < NT; ++j) {
        const int col = j * 16 + ln;
        float y = (vals[j][r] - mean) * rstd * lng[col] + lnb[col];
        ((float*)Cv)[(size_t)row * 256 + col] = y;
        if (obf) obf[(size_t)row * 256 + col] = f2bf(y);
      }
    }
    return;
  }

#pragma unroll
  for (int i = 0; i < MT; ++i)
#pragma unroll
    for (int j = 0; j < NT; ++j) {
      const int col = n0 + j * 16 + ln;
      const float bsv = bias[col];
      const int row0 = m0 + wm + i * 16 + quad * 4;
      float vals[4];
#pragma unroll
      for (int r = 0; r < 4; ++r) {
        float v = acc[i][j][r] + bsv;
        if (EPI == EPI_GELU) v = 0.5f * v * (1.0f + erff(v * 0.70710678f));
        vals[r] = v;
      }
      if (VSPLIT && col >= 512) {
        ushort4 pk;
        pk.x = f2bf(vals[0]); pk.y = f2bf(vals[1]);
        pk.z = f2bf(vals[2]); pk.w = f2bf(vals[3]);
        *(ushort4*)(vt + (size_t)((row0 >> 10) * 256 + (col - 512)) * T_SZ +
                    (row0 & 1023)) = pk;
      } else if (OUTBF) {
#pragma unroll
        for (int r = 0; r < 4; ++r)
          ((u16*)Cv)[(size_t)(row0 + r) * ldc + col] = f2bf(vals[r]);
      } else {
#pragma unroll
        for (int r = 0; r < 4; ++r)
          ((float*)Cv)[(size_t)(row0 + r) * ldc + col] = vals[r];
      }
    }
}

// ---------------------------------------------------------------------------
// Barrier-free MFMA flash attention (one wave = 16 q rows, paired balance).
// qk: [8192][512] bf16 (Q cols 0:256, K cols 256:512); vt transposed V.
// ---------------------------------------------------------------------------
__global__ __launch_bounds__(256)
void attn_flash(const u16* __restrict__ qk, const u16* __restrict__ vt,
                u16* __restrict__ outp) {
  __shared__ u16 Ps[4][16][72];
  const int tid = threadIdx.x;
  const int w = tid >> 6, lane = tid & 63;
  const int ln = lane & 15, quad = lane >> 4, kq8 = quad * 8;
  const int wu = blockIdx.x * 4 + w;
  const int bh = wu >> 6, s = wu & 63;
  const int qt = (s & 1) ? (63 - (s >> 1)) : (s >> 1);
  const int q0 = qt * 16;
  const int b = bh >> 2, h = bh & 3;
  const u16* base = qk + (size_t)b * T_SZ * 512;
  const u16* vbase = vt + (size_t)bh * 64 * T_SZ;

  bf16x8 qf[2];
#pragma unroll
  for (int ks = 0; ks < 2; ++ks)
    qf[ks] = *(const bf16x8*)(base + (size_t)(q0 + ln) * 512 + h * 64 +
                              ks * 32 + kq8);
  const short ob = (short)0x3F80;
  const bf16x8 ones = {ob, ob, ob, ob, ob, ob, ob, ob};

  f32x4 O[4] = {};
  f32x4 l_acc = {};
  const int ntiles = (qt >> 2) + 1;
  for (int jt = 0; jt < ntiles; ++jt) {
    const int c0 = jt * 64;
    f32x4 sv[4] = {};
#pragma unroll
    for (int ks = 0; ks < 2; ++ks)
#pragma unroll
      for (int j = 0; j < 4; ++j) {
        bf16x8 kf = *(const bf16x8*)(base + (size_t)(c0 + j * 16 + ln) * 512 +
                                     256 + h * 64 + ks * 32 + kq8);
        sv[j] = __builtin_amdgcn_mfma_f32_16x16x32_bf16(qf[ks], kf, sv[j], 0, 0, 0);
      }
    const bool need_mask = (c0 + 63 > q0);
#pragma unroll
    for (int j = 0; j < 4; ++j)
#pragma unroll
      for (int r = 0; r < 4; ++r) {
        float p = __expf(sv[j][r] * 0.125f);
        if (need_mask && (c0 + j * 16 + ln > q0 + quad * 4 + r)) p = 0.f;
        Ps[w][quad * 4 + r][j * 16 + ln] = f2bf(p);
      }
#pragma unroll
    for (int ks = 0; ks < 2; ++ks) {
      bf16x8 pf = *(const bf16x8*)&Ps[w][ln][ks * 32 + kq8];
      l_acc = __builtin_amdgcn_mfma_f32_16x16x32_bf16(pf, ones, l_acc, 0, 0, 0);
#pragma unroll
      for (int j = 0; j < 4; ++j) {
        bf16x8 vf = *(const bf16x8*)(vbase + (size_t)(j * 16 + ln) * T_SZ +
                                     c0 + ks * 32 + kq8);
        O[j] = __builtin_amdgcn_mfma_f32_16x16x32_bf16(pf, vf, O[j], 0, 0, 0);
      }
    }
  }
  u16* op = outp + (size_t)b * T_SZ * 256;
#pragma unroll
  for (int r = 0; r < 4; ++r) {
    const float inv = 1.f / l_acc[r];
#pragma unroll
    for (int j = 0; j < 4; ++j)
      op[(size_t)(q0 + quad * 4 + r) * 256 + h * 64 + j * 16 + ln] =
          f2bf(O[j][r] * inv);
  }
}

// ---------------------------------------------------------------------------
__device__ __forceinline__ float ln_finish(float v, float s1, float s2,
                                           float g, float bb) {
  float mean = s1 * (1.f / 256.f);
  float var = s2 * (1.f / 256.f) - mean * mean;
  return (v - mean) * rsqrtf(var + 1e-5f) * g + bb;
}

// states = LN3(seq + 0.5*(local_cumsum + carry)) -> bf16; t==1023 also LN4.
__global__ __launch_bounds__(256)
void ln34_kernel(const float* __restrict__ deltas, const float* __restrict__ scr,
                 const float* __restrict__ seq, const float* __restrict__ g3,
                 const float* __restrict__ b3, const float* __restrict__ g4,
                 const float* __restrict__ b4, u16* __restrict__ st,
                 float* __restrict__ fss) {
  __shared__ float tmp[4];
  const int row = blockIdx.x;
  const int b = row >> 10, t = row & 1023;
  const int d = threadIdx.x;
  float v = seq[b * 256 + d] +
            0.5f * (deltas[(size_t)row * 256 + d] +
                    scr[(size_t)(b * 32 + (t >> 5)) * 256 + d]);
  float s1 = block_reduce_sum(v, tmp);
  float s2 = block_reduce_sum(v * v, tmp);
  float y = ln_finish(v, s1, s2, g3[d], b3[d]);
  st[(size_t)row * 256 + d] = f2bf(y);
  if (t == 1023) {
    float t1s = block_reduce_sum(y, tmp);
    float t2s = block_reduce_sum(y * y, tmp);
    fss[b * 256 + d] = ln_finish(y, t1s, t2s, g4[d], b4[d]);
  }
}

// ---------------------------------------------------------------------------
// Fused depthwise conv (window 8) + EMA local pass. comb [8192][512]:
// cols 0:256 conv, 256:512 local EMA.
// ---------------------------------------------------------------------------
__global__ __launch_bounds__(256)
void emaconv_kernel(const float* __restrict__ x, const float* __restrict__ cw,
                    const float* __restrict__ cb, u16* __restrict__ comb,
                    float* __restrict__ scr) {
  const int bc = blockIdx.x;
  const int b = bc >> 5, ch = bc & 31;
  const int d = threadIdx.x;
  const int t0 = ch * 32;
  float wreg[8];
#pragma unroll
  for (int j = 0; j < 8; ++j) wreg[j] = cw[d * 8 + j];
  const float bias = cb[d];
  float xw[8];
#pragma unroll
  for (int j = 0; j < 7; ++j) {
    const int ts = t0 - 7 + j;
    xw[j] = (ts >= 0) ? x[(size_t)(b * T_SZ + ts) * 256 + d] : 0.f;
  }
  float c = 0.f;
#pragma unroll
  for (int tl = 0; tl < 32; ++tl) {
    const size_t row = (size_t)(b * T_SZ + t0 + tl);
    xw[7] = x[row * 256 + d];
    float conv = bias;
#pragma unroll
    for (int j = 0; j < 8; ++j) conv = fmaf(xw[j], wreg[j], conv);
    c = 0.9f * c + 0.1f * xw[7];
    comb[row * 512 + d] = f2bf(conv);
    comb[row * 512 + 256 + d] = f2bf(c);
#pragma unroll
    for (int j = 0; j < 7; ++j) xw[j] = xw[j + 1];
  }
  scr[(size_t)bc * 256 + d] = c;
}

__global__ __launch_bounds__(256)
void ema_b_kernel(float* __restrict__ scr) {
  const int b = blockIdx.x, d = threadIdx.x;
  const float q32 = 0.03433683820292512f;  // 0.9^32
  float carry = 0.f;
  for (int ch = 0; ch < 32; ++ch) {
    const size_t idx = (size_t)(b * 32 + ch) * 256 + d;
    float e = scr[idx];
    scr[idx] = carry;
    carry = e + q32 * carry;
  }
}

__global__ __launch_bounds__(256)
void ema_c_kernel(u16* __restrict__ comb, const float* __restrict__ scr,
                  float* __restrict__ fts) {
  const int row = blockIdx.x;
  const int b = row >> 10, t = row & 1023;
  const int d = threadIdx.x;
  const int ch = t >> 5, tl = t & 31;
  float carry = scr[(size_t)(b * 32 + ch) * 256 + d];
  float l = bf2f(comb[(size_t)row * 512 + 256 + d]);
  float y = fmaf(__powf(0.9f, (float)(tl + 1)), carry, l);
  comb[(size_t)row * 512 + 256 + d] = f2bf(y);
  if (t == 1023) fts[b * 256 + d] = y;
}

__global__ __launch_bounds__(256)
void cs_a_kernel(float* __restrict__ deltas, float* __restrict__ scr) {
  const int bc = blockIdx.x;
  const int b = bc >> 5, ch = bc & 31;
  const int d = threadIdx.x;
  const int t0 = ch * 32;
  float c = 0.f;
  for (int tl = 0; tl < 32; ++tl) {
    const size_t idx = (size_t)(b * T_SZ + t0 + tl) * 256 + d;
    c += deltas[idx];
    deltas[idx] = c;
  }
  scr[(size_t)bc * 256 + d] = c;
}

__global__ __launch_bounds__(256)
void cs_b_kernel(float* __restrict__ scr) {
  const int b = blockIdx.x, d = threadIdx.x;
  float carry = 0.f;
  for (int ch = 0; ch < 32; ++ch) {
    const size_t idx = (size_t)(b * 32 + ch) * 256 + d;
    float e = scr[idx];
    scr[idx] = carry;
    carry += e;
  }
}

// ---------------------------------------------------------------------------
extern "C" void kernel_launch(void* const* d_in, const int* in_sizes, int n_in,
                              void* d_out, int out_size, void* d_ws,
                              size_t ws_size, hipStream_t stream) {
  (void)in_sizes; (void)n_in; (void)out_size; (void)ws_size;
  const float* parallel_repr = (const float*)d_in[0];
  const float* sequential_state = (const float*)d_in[1];
  const float* in_proj_b = (const float*)d_in[4];
  const float* out_proj_b = (const float*)d_in[6];
  const float* conv_w = (const float*)d_in[7];
  const float* conv_b = (const float*)d_in[8];
  const float* p2s_b = (const float*)d_in[10];
  const float* s2p_b = (const float*)d_in[12];
  const float* trans_b1 = (const float*)d_in[14];
  const float* trans_b2 = (const float*)d_in[16];
  const float* ffn_b1 = (const float*)d_in[18];
  const float* ffn_b2 = (const float*)d_in[20];
  const float* ln1_s = (const float*)d_in[21];
  const float* ln1_b = (const float*)d_in[22];
  const float* ln2_s = (const float*)d_in[23];
  const float* ln2_b = (const float*)d_in[24];
  const float* ln3_s = (const float*)d_in[25];
  const float* ln3_b = (const float*)d_in[26];
  const float* ln4_s = (const float*)d_in[27];
  const float* ln4_b = (const float*)d_in[28];

  char* ws = (char*)d_ws;
  u16* qk_bf = (u16*)(ws + OFF_QK);
  u16* attn_bf = (u16*)(ws + OFF_ATTN);
  u16* f_bf = (u16*)(ws + OFF_F);
  u16* vt = (u16*)(ws + OFF_VT);
  float* x = (float*)(ws + OFF_X);
  u16* comb = (u16*)(ws + OFF_COMB);
  u16* pr_bf = (u16*)(ws + OFF_PRBF);
  u16* x_bf = (u16*)(ws + OFF_XBF);
  float* fbuf = (float*)(ws + OFF_FB);
  u16* wb = (u16*)(ws + OFF_WB);
  u16* w1x = (u16*)(ws + OFF_W1X);
  u16* w1s = (u16*)(ws + OFF_W1S);
  float* scr = (float*)(ws + OFF_SCR);
  float* b1x = (float*)(ws + OFF_B1X);
  float* b1s = (float*)(ws + OFF_B1S);
  u16* h_bf = (u16*)(ws + OFF_H);
  u16* states_bf = (u16*)(ws + OFF_STATES);
  float* out = (float*)d_out;
  float* out_fss = out + S_ELT;
  float* out_fts = out + S_ELT + 2048;

  const dim3 blk(256);

  // 0. weights + parallel_repr -> bf16
  wconv_kernel<<<3456, blk, 0, stream>>>(
      (const float*)d_in[3], (const float*)d_in[5], (const float*)d_in[9],
      (const float*)d_in[11], (const float*)d_in[13], (const float*)d_in[15],
      (const float*)d_in[17], (const float*)d_in[19], parallel_repr, wb, pr_bf);
  // 1. fold p2s into t1, s2p into ffn1 (fp32 sources)
  wfold_kernel<<<1536, blk, 0, stream>>>(
      (const float*)d_in[13], trans_b1, (const float*)d_in[9], p2s_b,
      (const float*)d_in[17], ffn_b1, (const float*)d_in[11], s2p_b,
      w1x, w1s, b1x, b1s);
  // 2. qkv projection: Q,K -> qk [8192][512]; V transposed -> vt
  mgemm<EPI_NONE, 128, 64, true, true><<<dim3(64, 12), blk, 0, stream>>>(
      pr_bf, 256, nullptr, 0, 256, wb + WB_INPROJ, 256, nullptr, 0, 0, 256,
      in_proj_b, qk_bf, 512, nullptr, nullptr, nullptr, nullptr, vt);
  // 3. attention (barrier-free)
  attn_flash<<<512, blk, 0, stream>>>(qk_bf, vt, attn_bf);
  // 4. x = LN1(PR + attn @ out_proj^T + b)  (fused GEMM+LN, x fp32 + bf16)
  mgemm<EPI_LN, 64, 256, false, false><<<dim3(128, 1), blk, 0, stream>>>(
      attn_bf, 256, nullptr, 0, 256, wb + WB_OUTPROJ, 256, nullptr, 0, 0, 256,
      out_proj_b, x, 256, parallel_repr, ln1_s, ln1_b, x_bf, nullptr);
  // 5-7. fused conv+EMA -> comb + traj summary
  emaconv_kernel<<<256, blk, 0, stream>>>(x, conv_w, conv_b, comb, scr);
  ema_b_kernel<<<8, blk, 0, stream>>>(scr);
  ema_c_kernel<<<8192, blk, 0, stream>>>(comb, scr, out_fts);
  // 8. h = gelu([x | conv | ema] @ [W1x | t1b | t1c]^T + bias1x)
  mgemm<EPI_GELU, 128, 64, true, false><<<dim3(64, 8), blk, 0, stream>>>(
      x_bf, 256, comb, 512, 256, w1x, 256, wb + WB_T1, 768, 0, 768, b1x, h_bf,
      512, nullptr, nullptr, nullptr, nullptr, nullptr);
  // 9. deltas = h @ t2^T + b2 -> fbuf (fp32)
  mgemm<EPI_NONE, 64, 64, false, false><<<dim3(128, 4), blk, 0, stream>>>(
      h_bf, 512, nullptr, 0, 512, wb + WB_T2, 512, nullptr, 0, 0, 512,
      trans_b2, fbuf, 256, nullptr, nullptr, nullptr, nullptr, nullptr);
  // 10-11. chunked cumsum
  cs_a_kernel<<<256, blk, 0, stream>>>(fbuf, scr);
  cs_b_kernel<<<8, blk, 0, stream>>>(scr);
  // 12. states = LN3(...) -> bf16; fused LN4 -> out_fss
  ln34_kernel<<<8192, blk, 0, stream>>>(fbuf, scr, sequential_state, ln3_s,
                                        ln3_b, ln4_s, ln4_b, states_bf, out_fss);
  // 13. f = gelu([x | states] @ [ffn1 | W1s]^T + bias1s)
  mgemm<EPI_GELU, 128, 64, true, false><<<dim3(64, 16), blk, 0, stream>>>(
      x_bf, 256, states_bf, 256, 256, wb + WB_F1, 256, w1s, 256, 256, 512, b1s,
      f_bf, 1024, nullptr, nullptr, nullptr, nullptr, nullptr);
  // 14. out = LN2(x + f @ ffn2^T + b2)  (fused GEMM+LN)
  mgemm<EPI_LN, 64, 256, false, false><<<dim3(128, 1), blk, 0, stream>>>(
      f_bf, 1024, nullptr, 0, 1024, wb + WB_F2, 1024, nullptr, 0, 0, 1024,
      ffn_b2, out, 256, x, ln2_s, ln2_b, nullptr, nullptr);
}

// Round 7
// 283.271 us; speedup vs baseline: 1.0661x; 1.0661x over previous
//
#include <hip/hip_runtime.h>
#include <math.h>

typedef unsigned short u16;
typedef __attribute__((ext_vector_type(8))) short bf16x8;
typedef __attribute__((ext_vector_type(4))) float f32x4;

#define D_MODEL 256
#define T_SZ 1024
constexpr size_t S_ELT = (size_t)8192 * 256;
constexpr size_t MB = 1024 * 1024;

// workspace byte offsets -- 268MB available, all disjoint (no aliasing)
constexpr size_t OFF_QK = 0;             // u16 [8192][512] Q|K (8MB)
constexpr size_t OFF_VT = 8 * MB;        // u16 [32][64][1024] V^T (4MB)
constexpr size_t OFF_ATTN = 12 * MB;     // u16 [8192][256] (4MB)
constexpr size_t OFF_X = 16 * MB;        // f32 [8192][256] (8MB)
constexpr size_t OFF_XBF = 24 * MB;      // u16 [8192][256] (4MB)
constexpr size_t OFF_COMB = 28 * MB;     // u16 [8192][512] conv|ema (8MB)
constexpr size_t OFF_XP = 36 * MB;       // u16 [8192][256] x+0.3*p2s (4MB)
constexpr size_t OFF_H = 40 * MB;        // u16 [8192][512] (8MB)
constexpr size_t OFF_FB = 48 * MB;       // f32 [8192][256] attn_out/deltas/ffn_out (8MB)
constexpr size_t OFF_STATES = 56 * MB;   // u16 [8192][256] (4MB)
constexpr size_t OFF_FFNIN = 60 * MB;    // u16 [8192][256] (4MB)
constexpr size_t OFF_F = 64 * MB;        // u16 [8192][1024] (16MB)
constexpr size_t OFF_PRBF = 80 * MB;     // u16 [8192][256] (4MB)
constexpr size_t OFF_WB = 84 * MB;       // u16 weights (2.75MB)
constexpr size_t OFF_SCR = 88 * MB;      // f32 65536 (ema carries, then cumsum)

// bf16 weight element offsets inside WB
constexpr int WB_INPROJ = 0;
constexpr int WB_OUTPROJ = 196608;
constexpr int WB_P2S = 262144;
constexpr int WB_S2P = 327680;
constexpr int WB_T1 = 393216;
constexpr int WB_T2 = 786432;
constexpr int WB_F1 = 917504;
constexpr int WB_F2 = 1179648;
constexpr int WB_TOTAL = 1441792;
constexpr int PR_TOTAL = 2097152;

__device__ __forceinline__ u16 f2bf(float f) {
  unsigned int u = __float_as_uint(f);
  u += 0x7fff + ((u >> 16) & 1);
  return (u16)(u >> 16);
}
__device__ __forceinline__ float bf2f(u16 s) {
  return __uint_as_float(((unsigned int)s) << 16);
}

// async global -> LDS, 16B per lane; LDS dst is wave-uniform base + lane*16B.
__device__ __forceinline__ void glds16(const u16* g, u16* l) {
  __builtin_amdgcn_global_load_lds(
      (const __attribute__((address_space(1))) void*)g,
      (__attribute__((address_space(3))) void*)l, 16, 0, 0);
}

__device__ __forceinline__ float block_reduce_sum(float v, float* tmp) {
#pragma unroll
  for (int o = 32; o > 0; o >>= 1) v += __shfl_down(v, o);
  const int lane = threadIdx.x & 63, wid = threadIdx.x >> 6;
  if (lane == 0) tmp[wid] = v;
  __syncthreads();
  v = tmp[0] + tmp[1] + tmp[2] + tmp[3];
  __syncthreads();
  return v;
}

// ---------------------------------------------------------------------------
// weight + parallel_repr fp32 -> bf16 conversion (single kernel)
// ---------------------------------------------------------------------------
__global__ __launch_bounds__(256)
void wconv_kernel(const float* w0, const float* w1, const float* w2,
                  const float* w3, const float* w4, const float* w5,
                  const float* w6, const float* w7, const float* pr,
                  u16* __restrict__ wb, u16* __restrict__ prb) {
  const int idx4 = (blockIdx.x * 256 + threadIdx.x) * 4;
  if (idx4 < WB_TOTAL) {
    const int offs[9] = {WB_INPROJ, WB_OUTPROJ, WB_P2S,  WB_S2P, WB_T1,
                         WB_T2,     WB_F1,      WB_F2,   WB_TOTAL};
    const float* srcs[8] = {w0, w1, w2, w3, w4, w5, w6, w7};
    int seg = 0;
    while (idx4 >= offs[seg + 1]) ++seg;
    float4 v = *(const float4*)(srcs[seg] + (idx4 - offs[seg]));
    unsigned int lo = (unsigned int)f2bf(v.x) | ((unsigned int)f2bf(v.y) << 16);
    unsigned int hi = (unsigned int)f2bf(v.z) | ((unsigned int)f2bf(v.w) << 16);
    *(uint2*)(wb + idx4) = make_uint2(lo, hi);
  } else {
    const int i4 = idx4 - WB_TOTAL;
    if (i4 < PR_TOTAL) {
      float4 v = *(const float4*)(pr + i4);
      unsigned int lo = (unsigned int)f2bf(v.x) | ((unsigned int)f2bf(v.y) << 16);
      unsigned int hi = (unsigned int)f2bf(v.z) | ((unsigned int)f2bf(v.w) << 16);
      *(uint2*)(prb + i4) = make_uint2(lo, hi);
    }
  }
}

// ---------------------------------------------------------------------------
// bf16 MFMA GEMM, fragment-ordered async LDS staging, BK=64.
// A and W may be split at k=ksplit between two sources.
// EPI_ADDSCALE: v = addsrc + 0.3*v. VSPLIT: cols>=512 transposed to vt.
// ---------------------------------------------------------------------------
enum { EPI_NONE = 0, EPI_GELU = 1, EPI_ADDSCALE = 2 };

template <int EPI, int BM, int BN, bool OUTBF, bool VSPLIT>
__global__ __launch_bounds__(256, 4)
void mgemm(const u16* __restrict__ A1, int lda1, const u16* __restrict__ A2,
           int lda2, int ksplit, const u16* __restrict__ W1, int ldw1,
           const u16* __restrict__ W2, int ldw2, int woff2, int K,
           const float* __restrict__ bias, void* __restrict__ Cv, int ldc,
           const float* __restrict__ addsrc, u16* __restrict__ vt) {
  __shared__ u16 As[BM * 64];
  __shared__ u16 Bs[BN * 64];
  const int tid = threadIdx.x;
  const int w = tid >> 6, lane = tid & 63;
  const int ln = lane & 15, quad = lane >> 4;
  const int m0 = blockIdx.x * BM;
  const int n0 = blockIdx.y * BN;
  constexpr int MT = BM / 64;   // rows per wave = MT*16 (4 waves split rows)
  constexpr int NT = BN / 16;   // col fragments per wave
  const int wm = w * (MT * 16);
  constexpr int APW = BM / 64;
  constexpr int BPW = BN / 64;

  f32x4 acc[MT][NT] = {};

  const int grow = lane >> 2;      // row within 16-row group
  const int gk8 = (lane & 3) * 8;  // k element offset

  for (int k0 = 0; k0 < K; k0 += 64) {
#pragma unroll
    for (int s = 0; s < 2; ++s) {
      const int kb = k0 + s * 32;
      const bool r1 = kb < ksplit;
      const u16* Ab = r1 ? A1 : A2;
      const int alda = r1 ? lda1 : lda2;
      const int ak = r1 ? kb : kb - ksplit;
#pragma unroll
      for (int p = 0; p < APW; ++p) {
        const int g = w * APW + p;
        glds16(Ab + (size_t)(m0 + g * 16 + grow) * alda + ak + gk8,
               As + s * BM * 32 + g * 512);
      }
      const u16* Wb = r1 ? W1 : W2;
      const int wlda = r1 ? ldw1 : ldw2;
      const int wk = r1 ? kb : kb - woff2;
#pragma unroll
      for (int p = 0; p < BPW; ++p) {
        const int g = w * BPW + p;
        glds16(Wb + (size_t)(n0 + g * 16 + grow) * wlda + wk + gk8,
               Bs + s * BN * 32 + g * 512);
      }
    }
    __syncthreads();
#pragma unroll
    for (int s = 0; s < 2; ++s) {
      const u16* abase = As + s * BM * 32 + (wm >> 4) * 512 + ln * 32 + quad * 8;
      const u16* bbase = Bs + s * BN * 32 + ln * 32 + quad * 8;
      bf16x8 af[MT], bv[NT];
#pragma unroll
      for (int i = 0; i < MT; ++i) af[i] = *(const bf16x8*)(abase + i * 512);
#pragma unroll
      for (int j = 0; j < NT; ++j) bv[j] = *(const bf16x8*)(bbase + j * 512);
#pragma unroll
      for (int i = 0; i < MT; ++i)
#pragma unroll
        for (int j = 0; j < NT; ++j)
          acc[i][j] = __builtin_amdgcn_mfma_f32_16x16x32_bf16(af[i], bv[j],
                                                              acc[i][j], 0, 0, 0);
    }
    __syncthreads();
  }

#pragma unroll
  for (int i = 0; i < MT; ++i)
#pragma unroll
    for (int j = 0; j < NT; ++j) {
      const int col = n0 + j * 16 + ln;
      const float bsv = bias[col];
      const int row0 = m0 + wm + i * 16 + quad * 4;
      float vals[4];
#pragma unroll
      for (int r = 0; r < 4; ++r) {
        float v = acc[i][j][r] + bsv;
        if (EPI == EPI_GELU) v = 0.5f * v * (1.0f + erff(v * 0.70710678f));
        if (EPI == EPI_ADDSCALE)
          v = addsrc[(size_t)(row0 + r) * 256 + col] + 0.3f * v;
        vals[r] = v;
      }
      if (VSPLIT && col >= 512) {
        ushort4 pk;
        pk.x = f2bf(vals[0]); pk.y = f2bf(vals[1]);
        pk.z = f2bf(vals[2]); pk.w = f2bf(vals[3]);
        *(ushort4*)(vt + (size_t)((row0 >> 10) * 256 + (col - 512)) * T_SZ +
                    (row0 & 1023)) = pk;
      } else if (OUTBF) {
#pragma unroll
        for (int r = 0; r < 4; ++r)
          ((u16*)Cv)[(size_t)(row0 + r) * ldc + col] = f2bf(vals[r]);
      } else {
#pragma unroll
        for (int r = 0; r < 4; ++r)
          ((float*)Cv)[(size_t)(row0 + r) * ldc + col] = vals[r];
      }
    }
}

// ---------------------------------------------------------------------------
// Barrier-free MFMA flash attention (one wave = 16 q rows, paired balance).
// qk: [8192][512] bf16 (Q cols 0:256, K cols 256:512); vt transposed V.
// ---------------------------------------------------------------------------
__global__ __launch_bounds__(256)
void attn_flash(const u16* __restrict__ qk, const u16* __restrict__ vt,
                u16* __restrict__ outp) {
  __shared__ u16 Ps[4][16][72];
  const int tid = threadIdx.x;
  const int w = tid >> 6, lane = tid & 63;
  const int ln = lane & 15, quad = lane >> 4, kq8 = quad * 8;
  const int wu = blockIdx.x * 4 + w;
  const int bh = wu >> 6, s = wu & 63;
  const int qt = (s & 1) ? (63 - (s >> 1)) : (s >> 1);
  const int q0 = qt * 16;
  const int b = bh >> 2, h = bh & 3;
  const u16* base = qk + (size_t)b * T_SZ * 512;
  const u16* vbase = vt + (size_t)bh * 64 * T_SZ;

  bf16x8 qf[2];
#pragma unroll
  for (int ks = 0; ks < 2; ++ks)
    qf[ks] = *(const bf16x8*)(base + (size_t)(q0 + ln) * 512 + h * 64 +
                              ks * 32 + kq8);
  const short ob = (short)0x3F80;
  const bf16x8 ones = {ob, ob, ob, ob, ob, ob, ob, ob};

  f32x4 O[4] = {};
  f32x4 l_acc = {};
  const int ntiles = (qt >> 2) + 1;
  for (int jt = 0; jt < ntiles; ++jt) {
    const int c0 = jt * 64;
    f32x4 sv[4] = {};
#pragma unroll
    for (int ks = 0; ks < 2; ++ks)
#pragma unroll
      for (int j = 0; j < 4; ++j) {
        bf16x8 kf = *(const bf16x8*)(base + (size_t)(c0 + j * 16 + ln) * 512 +
                                     256 + h * 64 + ks * 32 + kq8);
        sv[j] = __builtin_amdgcn_mfma_f32_16x16x32_bf16(qf[ks], kf, sv[j], 0, 0, 0);
      }
    const bool need_mask = (c0 + 63 > q0);
#pragma unroll
    for (int j = 0; j < 4; ++j)
#pragma unroll
      for (int r = 0; r < 4; ++r) {
        float p = __expf(sv[j][r] * 0.125f);
        if (need_mask && (c0 + j * 16 + ln > q0 + quad * 4 + r)) p = 0.f;
        Ps[w][quad * 4 + r][j * 16 + ln] = f2bf(p);
      }
#pragma unroll
    for (int ks = 0; ks < 2; ++ks) {
      bf16x8 pf = *(const bf16x8*)&Ps[w][ln][ks * 32 + kq8];
      l_acc = __builtin_amdgcn_mfma_f32_16x16x32_bf16(pf, ones, l_acc, 0, 0, 0);
#pragma unroll
      for (int j = 0; j < 4; ++j) {
        bf16x8 vf = *(const bf16x8*)(vbase + (size_t)(j * 16 + ln) * T_SZ +
                                     c0 + ks * 32 + kq8);
        O[j] = __builtin_amdgcn_mfma_f32_16x16x32_bf16(pf, vf, O[j], 0, 0, 0);
      }
    }
  }
  u16* op = outp + (size_t)b * T_SZ * 256;
#pragma unroll
  for (int r = 0; r < 4; ++r) {
    const float inv = 1.f / l_acc[r];
#pragma unroll
    for (int j = 0; j < 4; ++j)
      op[(size_t)(q0 + quad * 4 + r) * 256 + h * 64 + j * 16 + ln] =
          f2bf(O[j][r] * inv);
  }
}

// ---------------------------------------------------------------------------
__device__ __forceinline__ float ln_finish(float v, float s1, float s2,
                                           float g, float bb) {
  float mean = s1 * (1.f / 256.f);
  float var = s2 * (1.f / 256.f) - mean * mean;
  return (v - mean) * rsqrtf(var + 1e-5f) * g + bb;
}

__global__ __launch_bounds__(256)
void ln_add_kernel(const float* __restrict__ a, const float* __restrict__ addsrc,
                   const float* __restrict__ g, const float* __restrict__ bb,
                   float* __restrict__ outp, u16* __restrict__ obf) {
  __shared__ float tmp[4];
  const size_t row = blockIdx.x;
  const int d = threadIdx.x;
  float v = a[row * 256 + d] + addsrc[row * 256 + d];
  float s1 = block_reduce_sum(v, tmp);
  float s2 = block_reduce_sum(v * v, tmp);
  float y = ln_finish(v, s1, s2, g[d], bb[d]);
  outp[row * 256 + d] = y;
  if (obf) obf[row * 256 + d] = f2bf(y);
}

// states = LN3(seq + 0.5*(local_cumsum + carry)) -> bf16; t==1023 also LN4.
__global__ __launch_bounds__(256)
void ln34_kernel(const float* __restrict__ deltas, const float* __restrict__ scr,
                 const float* __restrict__ seq, const float* __restrict__ g3,
                 const float* __restrict__ b3, const float* __restrict__ g4,
                 const float* __restrict__ b4, u16* __restrict__ st,
                 float* __restrict__ fss) {
  __shared__ float tmp[4];
  const int row = blockIdx.x;
  const int b = row >> 10, t = row & 1023;
  const int d = threadIdx.x;
  float v = seq[b * 256 + d] +
            0.5f * (deltas[(size_t)row * 256 + d] +
                    scr[(size_t)(b * 32 + (t >> 5)) * 256 + d]);
  float s1 = block_reduce_sum(v, tmp);
  float s2 = block_reduce_sum(v * v, tmp);
  float y = ln_finish(v, s1, s2, g3[d], b3[d]);
  st[(size_t)row * 256 + d] = f2bf(y);
  if (t == 1023) {
    float t1s = block_reduce_sum(y, tmp);
    float t2s = block_reduce_sum(y * y, tmp);
    fss[b * 256 + d] = ln_finish(y, t1s, t2s, g4[d], b4[d]);
  }
}

// ---------------------------------------------------------------------------
// Fused depthwise conv (window 8) + EMA local pass. comb [8192][512]:
// cols 0:256 conv, 256:512 local EMA.
// ---------------------------------------------------------------------------
__global__ __launch_bounds__(256)
void emaconv_kernel(const float* __restrict__ x, const float* __restrict__ cw,
                    const float* __restrict__ cb, u16* __restrict__ comb,
                    float* __restrict__ scr) {
  const int bc = blockIdx.x;
  const int b = bc >> 5, ch = bc & 31;
  const int d = threadIdx.x;
  const int t0 = ch * 32;
  float wreg[8];
#pragma unroll
  for (int j = 0; j < 8; ++j) wreg[j] = cw[d * 8 + j];
  const float bias = cb[d];
  float xw[8];
#pragma unroll
  for (int j = 0; j < 7; ++j) {
    const int ts = t0 - 7 + j;
    xw[j] = (ts >= 0) ? x[(size_t)(b * T_SZ + ts) * 256 + d] : 0.f;
  }
  float c = 0.f;
#pragma unroll
  for (int tl = 0; tl < 32; ++tl) {
    const size_t row = (size_t)(b * T_SZ + t0 + tl);
    xw[7] = x[row * 256 + d];
    float conv = bias;
#pragma unroll
    for (int j = 0; j < 8; ++j) conv = fmaf(xw[j], wreg[j], conv);
    c = 0.9f * c + 0.1f * xw[7];
    comb[row * 512 + d] = f2bf(conv);
    comb[row * 512 + 256 + d] = f2bf(c);
#pragma unroll
    for (int j = 0; j < 7; ++j) xw[j] = xw[j + 1];
  }
  scr[(size_t)bc * 256 + d] = c;
}

__global__ __launch_bounds__(256)
void ema_b_kernel(float* __restrict__ scr) {
  const int b = blockIdx.x, d = threadIdx.x;
  const float q32 = 0.03433683820292512f;  // 0.9^32
  float carry = 0.f;
  for (int ch = 0; ch < 32; ++ch) {
    const size_t idx = (size_t)(b * 32 + ch) * 256 + d;
    float e = scr[idx];
    scr[idx] = carry;
    carry = e + q32 * carry;
  }
}

__global__ __launch_bounds__(256)
void ema_c_kernel(u16* __restrict__ comb, const float* __restrict__ scr,
                  float* __restrict__ fts) {
  const int row = blockIdx.x;
  const int b = row >> 10, t = row & 1023;
  const int d = threadIdx.x;
  const int ch = t >> 5, tl = t & 31;
  float carry = scr[(size_t)(b * 32 + ch) * 256 + d];
  float l = bf2f(comb[(size_t)row * 512 + 256 + d]);
  float y = fmaf(__powf(0.9f, (float)(tl + 1)), carry, l);
  comb[(size_t)row * 512 + 256 + d] = f2bf(y);
  if (t == 1023) fts[b * 256 + d] = y;
}

__global__ __launch_bounds__(256)
void cs_a_kernel(float* __restrict__ deltas, float* __restrict__ scr) {
  const int bc = blockIdx.x;
  const int b = bc >> 5, ch = bc & 31;
  const int d = threadIdx.x;
  const int t0 = ch * 32;
  float c = 0.f;
  for (int tl = 0; tl < 32; ++tl) {
    const size_t idx = (size_t)(b * T_SZ + t0 + tl) * 256 + d;
    c += deltas[idx];
    deltas[idx] = c;
  }
  scr[(size_t)bc * 256 + d] = c;
}

__global__ __launch_bounds__(256)
void cs_b_kernel(float* __restrict__ scr) {
  const int b = blockIdx.x, d = threadIdx.x;
  float carry = 0.f;
  for (int ch = 0; ch < 32; ++ch) {
    const size_t idx = (size_t)(b * 32 + ch) * 256 + d;
    float e = scr[idx];
    scr[idx] = carry;
    carry += e;
  }
}

// ---------------------------------------------------------------------------
extern "C" void kernel_launch(void* const* d_in, const int* in_sizes, int n_in,
                              void* d_out, int out_size, void* d_ws,
                              size_t ws_size, hipStream_t stream) {
  (void)in_sizes; (void)n_in; (void)out_size; (void)ws_size;
  const float* parallel_repr = (const float*)d_in[0];
  const float* sequential_state = (const float*)d_in[1];
  const float* in_proj_b = (const float*)d_in[4];
  const float* out_proj_b = (const float*)d_in[6];
  const float* conv_w = (const float*)d_in[7];
  const float* conv_b = (const float*)d_in[8];
  const float* p2s_b = (const float*)d_in[10];
  const float* s2p_b = (const float*)d_in[12];
  const float* trans_b1 = (const float*)d_in[14];
  const float* trans_b2 = (const float*)d_in[16];
  const float* ffn_b1 = (const float*)d_in[18];
  const float* ffn_b2 = (const float*)d_in[20];
  const float* ln1_s = (const float*)d_in[21];
  const float* ln1_b = (const float*)d_in[22];
  const float* ln2_s = (const float*)d_in[23];
  const float* ln2_b = (const float*)d_in[24];
  const float* ln3_s = (const float*)d_in[25];
  const float* ln3_b = (const float*)d_in[26];
  const float* ln4_s = (const float*)d_in[27];
  const float* ln4_b = (const float*)d_in[28];

  char* ws = (char*)d_ws;
  u16* qk_bf = (u16*)(ws + OFF_QK);
  u16* vt = (u16*)(ws + OFF_VT);
  u16* attn_bf = (u16*)(ws + OFF_ATTN);
  float* x = (float*)(ws + OFF_X);
  u16* x_bf = (u16*)(ws + OFF_XBF);
  u16* comb = (u16*)(ws + OFF_COMB);
  u16* xp_bf = (u16*)(ws + OFF_XP);
  u16* h_bf = (u16*)(ws + OFF_H);
  float* fbuf = (float*)(ws + OFF_FB);
  u16* states_bf = (u16*)(ws + OFF_STATES);
  u16* ffn_in = (u16*)(ws + OFF_FFNIN);
  u16* f_bf = (u16*)(ws + OFF_F);
  u16* pr_bf = (u16*)(ws + OFF_PRBF);
  u16* wb = (u16*)(ws + OFF_WB);
  float* scr = (float*)(ws + OFF_SCR);
  float* out = (float*)d_out;
  float* out_fss = out + S_ELT;
  float* out_fts = out + S_ELT + 2048;

  const dim3 blk(256);

  // 0. weights + parallel_repr -> bf16
  wconv_kernel<<<3456, blk, 0, stream>>>(
      (const float*)d_in[3], (const float*)d_in[5], (const float*)d_in[9],
      (const float*)d_in[11], (const float*)d_in[13], (const float*)d_in[15],
      (const float*)d_in[17], (const float*)d_in[19], parallel_repr, wb, pr_bf);
  // 1. qkv projection: Q,K -> qk [8192][512]; V transposed -> vt
  mgemm<EPI_NONE, 128, 64, true, true><<<dim3(64, 12), blk, 0, stream>>>(
      pr_bf, 256, pr_bf, 256, 256, wb + WB_INPROJ, 256, wb + WB_INPROJ, 256, 0,
      256, in_proj_b, qk_bf, 512, nullptr, vt);
  // 2. attention (barrier-free)
  attn_flash<<<512, blk, 0, stream>>>(qk_bf, vt, attn_bf);
  // 3. attn_out = attn @ out_proj^T + b -> fbuf (fp32)
  mgemm<EPI_NONE, 64, 64, false, false><<<dim3(128, 4), blk, 0, stream>>>(
      attn_bf, 256, attn_bf, 256, 256, wb + WB_OUTPROJ, 256, wb + WB_OUTPROJ,
      256, 0, 256, out_proj_b, fbuf, 256, nullptr, nullptr);
  // 4. x = LN1(PR + attn_out), also emit x_bf
  ln_add_kernel<<<8192, blk, 0, stream>>>(parallel_repr, fbuf, ln1_s, ln1_b, x,
                                          x_bf);
  // 5-7. fused conv+EMA -> comb + traj summary
  emaconv_kernel<<<256, blk, 0, stream>>>(x, conv_w, conv_b, comb, scr);
  ema_b_kernel<<<8, blk, 0, stream>>>(scr);
  ema_c_kernel<<<8192, blk, 0, stream>>>(comb, scr, out_fts);
  // 8. xp = x + 0.3*(x @ p2s^T + b)  -> bf16
  mgemm<EPI_ADDSCALE, 64, 64, true, false><<<dim3(128, 4), blk, 0, stream>>>(
      x_bf, 256, x_bf, 256, 256, wb + WB_P2S, 256, wb + WB_P2S, 256, 0, 256,
      p2s_b, xp_bf, 256, x, nullptr);
  // 9. h = gelu([xp | conv | ema] @ t1^T + b1)  (split-A, K=768)
  mgemm<EPI_GELU, 128, 64, true, false><<<dim3(64, 8), blk, 0, stream>>>(
      xp_bf, 256, comb, 512, 256, wb + WB_T1, 768, wb + WB_T1, 768, 0, 768,
      trans_b1, h_bf, 512, nullptr, nullptr);
  // 10. deltas = h @ t2^T + b2 -> fbuf (fp32)
  mgemm<EPI_NONE, 64, 64, false, false><<<dim3(128, 4), blk, 0, stream>>>(
      h_bf, 512, h_bf, 512, 512, wb + WB_T2, 512, wb + WB_T2, 512, 0, 512,
      trans_b2, fbuf, 256, nullptr, nullptr);
  // 11-12. chunked cumsum
  cs_a_kernel<<<256, blk, 0, stream>>>(fbuf, scr);
  cs_b_kernel<<<8, blk, 0, stream>>>(scr);
  // 13. states = LN3(...) -> bf16; fused LN4 -> out_fss
  ln34_kernel<<<8192, blk, 0, stream>>>(fbuf, scr, sequential_state, ln3_s,
                                        ln3_b, ln4_s, ln4_b, states_bf, out_fss);
  // 14. ffn_in = x + 0.3*(states @ s2p^T + b) -> bf16
  mgemm<EPI_ADDSCALE, 64, 64, true, false><<<dim3(128, 4), blk, 0, stream>>>(
      states_bf, 256, states_bf, 256, 256, wb + WB_S2P, 256, wb + WB_S2P, 256,
      0, 256, s2p_b, ffn_in, 256, x, nullptr);
  // 15. f = gelu(ffn_in @ ffn1^T + b1)
  mgemm<EPI_GELU, 128, 64, true, false><<<dim3(64, 16), blk, 0, stream>>>(
      ffn_in, 256, ffn_in, 256, 256, wb + WB_F1, 256, wb + WB_F1, 256, 0, 256,
      ffn_b1, f_bf, 1024, nullptr, nullptr);
  // 16. ffn_out = f @ ffn2^T + b2 -> fbuf
  mgemm<EPI_NONE, 64, 64, false, false><<<dim3(128, 4), blk, 0, stream>>>(
      f_bf, 1024, f_bf, 1024, 1024, wb + WB_F2, 1024, wb + WB_F2, 1024, 0,
      1024, ffn_b2, fbuf, 256, nullptr, nullptr);
  // 17. out = LN2(x + ffn_out)
  ln_add_kernel<<<8192, blk, 0, stream>>>(x, fbuf, ln2_s, ln2_b, out, nullptr);
}